// Round 1
// baseline (164.591 us; speedup 1.0000x reference)
//
#include <hip/hip_runtime.h>

// Problem constants (fixed by the reference)
constexpr int BN = 64;          // batch
constexpr int HH = 28;          // height
constexpr int WW = 28;          // width
constexpr int CC = 1024;        // channels
constexpr int HWP = HH * WW;    // 784 spatial positions

// ---------------------------------------------------------------------------
// Kernel 1: per-(b,c) spatial argmax over 784 positions.
// Grid: BN * (CC/64) = 1024 blocks, 256 threads.
// Thread t: channel cl = t & 63, spatial-split s = t >> 6 (4 splits x 196).
// Lanes 0..63 hit consecutive channels -> fully coalesced 256B transactions.
// Strict '>' keeps the FIRST occurrence of the max (matches jnp.argmax);
// the cross-split reduce walks s=0..3 in order, preserving tie order.
// Output: packed (i_max << 8) | j_max per (b,c).
// ---------------------------------------------------------------------------
__global__ __launch_bounds__(256) void argmax_pack_kernel(
    const float* __restrict__ in, int* __restrict__ peak) {
    __shared__ float s_val[4][64];
    __shared__ int   s_idx[4][64];

    const int t   = threadIdx.x;
    const int cl  = t & 63;        // channel within group
    const int s   = t >> 6;        // spatial split 0..3
    const int blk = blockIdx.x;
    const int b   = blk >> 4;      // 16 channel-groups per batch
    const int cg  = blk & 15;
    const int c   = cg * 64 + cl;

    const float* base = in + ((size_t)b * HWP) * CC + c;

    const int p0 = s * 196;
    float m  = -__builtin_inff();
    int   mi = p0;
    #pragma unroll 4
    for (int p = p0; p < p0 + 196; ++p) {
        const float v = base[(size_t)p * CC];
        if (v > m) { m = v; mi = p; }
    }

    s_val[s][cl] = m;
    s_idx[s][cl] = mi;
    __syncthreads();

    if (s == 0) {
        float bm = m;
        int   bi = mi;
        #pragma unroll
        for (int k = 1; k < 4; ++k) {
            const float v = s_val[k][cl];
            if (v > bm) { bm = v; bi = s_idx[k][cl]; }
        }
        const int imax = bi / 28;
        const int jmax = bi - imax * 28;
        peak[b * CC + c] = (imax << 8) | jmax;
    }
}

// ---------------------------------------------------------------------------
// Kernel 2: out = in * mask, float4-vectorized over channels.
// Flat float4 index e: c4 = e & 255 (CC/4=256), rest = e >> 8 = b*784 + p.
// Mask math reproduces the reference fp32 op order exactly:
//   mask = tau * max(1 - (4*d)/28, -1),  tau = 0.5/784
// ---------------------------------------------------------------------------
__global__ __launch_bounds__(256) void apply_mask_kernel(
    const float4* __restrict__ in4, const int* __restrict__ peak,
    float4* __restrict__ out4) {
    constexpr int   NV  = BN * HWP * (CC / 4);   // 12,845,056 float4s
    constexpr float tau = 0.5f / 784.0f;

    const int stride = gridDim.x * blockDim.x;
    for (int e = blockIdx.x * blockDim.x + threadIdx.x; e < NV; e += stride) {
        const int c4   = e & 255;
        const int rest = e >> 8;          // b*784 + p
        const int b    = rest / 784;
        const int p    = rest - b * 784;
        const int i    = p / 28;
        const int j    = p - i * 28;

        const float4 v  = in4[e];
        const int4   pk = reinterpret_cast<const int4*>(peak)[b * 256 + c4];

        float4 o;
        {
            const int d = abs(i - (pk.x >> 8)) + abs(j - (pk.x & 255));
            o.x = v.x * (fmaxf(1.0f - (4.0f * (float)d) / 28.0f, -1.0f) * tau);
        }
        {
            const int d = abs(i - (pk.y >> 8)) + abs(j - (pk.y & 255));
            o.y = v.y * (fmaxf(1.0f - (4.0f * (float)d) / 28.0f, -1.0f) * tau);
        }
        {
            const int d = abs(i - (pk.z >> 8)) + abs(j - (pk.z & 255));
            o.z = v.z * (fmaxf(1.0f - (4.0f * (float)d) / 28.0f, -1.0f) * tau);
        }
        {
            const int d = abs(i - (pk.w >> 8)) + abs(j - (pk.w & 255));
            o.w = v.w * (fmaxf(1.0f - (4.0f * (float)d) / 28.0f, -1.0f) * tau);
        }
        out4[e] = o;
    }
}

extern "C" void kernel_launch(void* const* d_in, const int* in_sizes, int n_in,
                              void* d_out, int out_size, void* d_ws, size_t ws_size,
                              hipStream_t stream) {
    const float* in  = (const float*)d_in[0];
    float*       out = (float*)d_out;
    int*         peak = (int*)d_ws;   // BN*CC ints = 256 KB, rewritten every call

    // Pass 1: per-(b,c) argmax -> packed peak coordinates.
    argmax_pack_kernel<<<BN * (CC / 64), 256, 0, stream>>>(in, peak);

    // Pass 2: elementwise mask multiply, grid-stride float4.
    apply_mask_kernel<<<2048, 256, 0, stream>>>(
        (const float4*)in, peak, (float4*)out);
}

// Round 3
// 96.474 us; speedup vs baseline: 1.7061x; 1.7061x over previous
//
#include <hip/hip_runtime.h>

// Problem constants (fixed by the reference)
constexpr int BN  = 64;         // batch
constexpr int HH  = 28;         // height
constexpr int WW  = 28;         // width
constexpr int CC  = 1024;       // channels
constexpr int HWP = HH * WW;    // 784 spatial positions
constexpr int CQ  = CC / 4;     // 256 float4 "quads" per position
constexpr float TAU = 0.5f / 784.0f;

// Native clang vector type — required by __builtin_nontemporal_store
// (HIP's float4 is a class and is rejected). Same 16-byte layout.
typedef float f32x4 __attribute__((ext_vector_type(4)));

// ---------------------------------------------------------------------------
// Kernel 1: per-(b,c) spatial argmax over 784 positions, float4-vectorized.
// Grid: BN * 16 = 1024 blocks (block = one batch x one 64-channel group).
// Thread t: channel-quad q = t & 15 (4 channels), spatial split s = t >> 4
// (16 splits x 49 positions). Each float4 load covers 4 consecutive channels;
// lanes 0..15 of a wave read 256 B contiguous per position row.
// Strict '>' with ascending p, then ascending-split LDS reduce -> exact
// first-occurrence semantics matching jnp.argmax.
// Output: packed (i_max << 8) | j_max per (b,c).
// ---------------------------------------------------------------------------
__global__ __launch_bounds__(256) void argmax_pack_kernel(
    const float4* __restrict__ in4, int* __restrict__ peak) {
    __shared__ float s_val[16][64];
    __shared__ int   s_idx[16][64];

    const int t  = threadIdx.x;
    const int q  = t & 15;          // channel quad within the 64-ch group
    const int s  = t >> 4;          // spatial split 0..15
    const int b  = blockIdx.x >> 4; // 16 channel-groups per batch
    const int cg = blockIdx.x & 15;

    const float4* base = in4 + (size_t)(b * HWP) * CQ + cg * 16 + q;

    const int p0 = s * 49;
    float mx = -__builtin_inff(), my = mx, mz = mx, mw = mx;
    int   ix = p0, iy = p0, iz = p0, iw = p0;
    #pragma unroll 7
    for (int k = 0; k < 49; ++k) {
        const int p = p0 + k;
        const float4 v = base[(size_t)p * CQ];
        if (v.x > mx) { mx = v.x; ix = p; }
        if (v.y > my) { my = v.y; iy = p; }
        if (v.z > mz) { mz = v.z; iz = p; }
        if (v.w > mw) { mw = v.w; iw = p; }
    }

    const int c4 = q * 4;
    s_val[s][c4 + 0] = mx; s_idx[s][c4 + 0] = ix;
    s_val[s][c4 + 1] = my; s_idx[s][c4 + 1] = iy;
    s_val[s][c4 + 2] = mz; s_idx[s][c4 + 2] = iz;
    s_val[s][c4 + 3] = mw; s_idx[s][c4 + 3] = iw;
    __syncthreads();

    if (t < 64) {
        float bm = s_val[0][t];
        int   bi = s_idx[0][t];
        #pragma unroll
        for (int k = 1; k < 16; ++k) {   // ascending split order = tie order
            const float v = s_val[k][t];
            if (v > bm) { bm = v; bi = s_idx[k][t]; }
        }
        const int im = bi / 28;
        const int jm = bi - im * 28;
        peak[b * CC + cg * 64 + t] = (im << 8) | jm;
    }
}

// ---------------------------------------------------------------------------
// Kernel 2: out = in * mask. Block = (batch, 49-position chunk); thread owns
// a fixed channel-quad for the whole chunk, so the peak int4 is loaded ONCE
// into registers. Mask values come from a 64-entry LDS LUT indexed by the
// integer L1 distance d in [0,54] — entries computed with exactly the
// reference's fp32 op order (tau * max(1 - 4d/28, -1)), so results are
// bit-identical to computing per element. Nontemporal stores keep the
// (L3-resident) input from being evicted by the output stream.
// ---------------------------------------------------------------------------
__global__ __launch_bounds__(256) void apply_mask_kernel(
    const float4* __restrict__ in4, const int* __restrict__ peak,
    float4* __restrict__ out4) {
    __shared__ float lut[64];

    const int t = threadIdx.x;
    if (t < 64) {
        lut[t] = TAU * fmaxf(1.0f - (4.0f * (float)t) / 28.0f, -1.0f);
    }

    const int b     = blockIdx.x >> 4;
    const int chunk = blockIdx.x & 15;

    const int4 pk = reinterpret_cast<const int4*>(peak)[b * CQ + t];
    const int imx = pk.x >> 8, jmx = pk.x & 255;
    const int imy = pk.y >> 8, jmy = pk.y & 255;
    const int imz = pk.z >> 8, jmz = pk.z & 255;
    const int imw = pk.w >> 8, jmw = pk.w & 255;
    __syncthreads();

    const int p0 = chunk * 49;
    int i = p0 / 28;
    int j = p0 - i * 28;

    const size_t off0 = (size_t)(b * HWP + p0) * CQ + t;
    const float4* src = in4 + off0;
    f32x4*        dst = reinterpret_cast<f32x4*>(out4 + off0);

    #pragma unroll 7
    for (int k = 0; k < 49; ++k) {
        const float4 v = src[(size_t)k * CQ];
        f32x4 o;
        o.x = v.x * lut[abs(i - imx) + abs(j - jmx)];
        o.y = v.y * lut[abs(i - imy) + abs(j - jmy)];
        o.z = v.z * lut[abs(i - imz) + abs(j - jmz)];
        o.w = v.w * lut[abs(i - imw) + abs(j - jmw)];
        __builtin_nontemporal_store(o, &dst[(size_t)k * CQ]);
        if (++j == 28) { j = 0; ++i; }
    }
}

extern "C" void kernel_launch(void* const* d_in, const int* in_sizes, int n_in,
                              void* d_out, int out_size, void* d_ws, size_t ws_size,
                              hipStream_t stream) {
    const float* in   = (const float*)d_in[0];
    float*       out  = (float*)d_out;
    int*         peak = (int*)d_ws;   // BN*CC ints = 256 KB, fully rewritten

    argmax_pack_kernel<<<BN * 16, 256, 0, stream>>>((const float4*)in, peak);
    apply_mask_kernel<<<BN * 16, 256, 0, stream>>>(
        (const float4*)in, peak, (float4*)out);
}

// Round 4
// 70.405 us; speedup vs baseline: 2.3378x; 1.3703x over previous
//
#include <hip/hip_runtime.h>

// Problem constants (fixed by the reference)
constexpr int BN  = 64;          // batch
constexpr int HH  = 28;          // height
constexpr int WW  = 28;          // width
constexpr int CC  = 1024;        // channels
constexpr int HWP = HH * WW;     // 784 spatial positions
constexpr int CQ  = CC / 4;      // 256 float4s per spatial position row
constexpr float TAU = 0.5f / 784.0f;

// Native clang vector type (required by __builtin_nontemporal_store; same
// 16-byte layout as float4).
typedef float f32x4 __attribute__((ext_vector_type(4)));

__device__ __forceinline__ int iabs(int x) { return x < 0 ? -x : x; }

// ---------------------------------------------------------------------------
// Fully fused kernel: one block = (batch b, 32-channel group cg).
// Thread t: channel-quad q = t&7 (4 channels), position split s3 = t>>3.
// Thread owns positions {s3 + 64k}, k = 0..11 (+k=12 if s3<16): 12-13 float4s
// held in NAMED registers (static indexing — no scratch).
//   Phase A: load all (coalesced: wave covers 8 positions x 128 B contiguous),
//            inline per-thread argmax for its 4 channels (strict '>', ascending
//            positions -> first-occurrence within the thread's subset).
//   Phase B: two-stage LDS reduce with (v > bv) || (v == bv && idx < bidx)
//            tie-break -> exact global first-occurrence (jnp.argmax).
//   Phase C: mask the SAME registers, nontemporal store. Input is read from
//            HBM exactly once; no tile staging.
// Mask: tau * max(1 - 4d/28, -1) == max(fma(d, -tau/7, tau), -tau) to within
// ~2 ulp of tau (abs impact <= ~1e-9, threshold 6.9e-5, headroom 7.6e-6).
// ---------------------------------------------------------------------------
__global__ __launch_bounds__(512, 4) void fused_mask_kernel(
    const f32x4* __restrict__ in4, f32x4* __restrict__ out4) {
  __shared__ float s_pv[64][32];
  __shared__ int   s_pi[64][32];
  __shared__ float s2v[8][32];
  __shared__ int   s2i[8][32];
  __shared__ int   s_peak[32];

  const int t  = threadIdx.x;
  const int q  = t & 7;          // channel quad within the 32-ch group
  const int s3 = t >> 3;         // position split 0..63
  const int b  = blockIdx.x >> 5;
  const int cg = blockIdx.x & 31;

  const size_t base = ((size_t)b * HWP + s3) * CQ + cg * 8 + q;
  const f32x4* src = in4 + base;
  f32x4*       dst = out4 + base;
  constexpr size_t KSTR = (size_t)64 * CQ;   // 64 positions per k-step

  const bool tail = (s3 < 16);   // positions 768..783 (wave-uniform predicate)

#define LIST12(X) X(0) X(1) X(2) X(3) X(4) X(5) X(6) X(7) X(8) X(9) X(10) X(11)

  // ---- Phase A: 12-13 independent loads into named registers ----
#define LOADK(k) const f32x4 vv##k = src[(size_t)(k) * KSTR];
  LIST12(LOADK)
#undef LOADK
  f32x4 vv12 = {0.0f, 0.0f, 0.0f, 0.0f};
  if (tail) vv12 = src[(size_t)12 * KSTR];

  // Inline per-thread argmax (4 channels), ascending positions, strict '>'.
  float bm0 = -__builtin_inff(), bm1 = bm0, bm2 = bm0, bm3 = bm0;
  int   bi0 = 0, bi1 = 0, bi2 = 0, bi3 = 0;
#define AMAXK(k) { const int p = s3 + 64 * (k); \
    if (vv##k.x > bm0) { bm0 = vv##k.x; bi0 = p; } \
    if (vv##k.y > bm1) { bm1 = vv##k.y; bi1 = p; } \
    if (vv##k.z > bm2) { bm2 = vv##k.z; bi2 = p; } \
    if (vv##k.w > bm3) { bm3 = vv##k.w; bi3 = p; } }
  LIST12(AMAXK)
#undef AMAXK
  if (tail) {
    const int p = s3 + 768;
    if (vv12.x > bm0) { bm0 = vv12.x; bi0 = p; }
    if (vv12.y > bm1) { bm1 = vv12.y; bi1 = p; }
    if (vv12.z > bm2) { bm2 = vv12.z; bi2 = p; }
    if (vv12.w > bm3) { bm3 = vv12.w; bi3 = p; }
  }

  // ---- Phase B: two-stage reduce with first-occurrence tie-break ----
  const int c0 = q * 4;
  s_pv[s3][c0 + 0] = bm0; s_pi[s3][c0 + 0] = bi0;
  s_pv[s3][c0 + 1] = bm1; s_pi[s3][c0 + 1] = bi1;
  s_pv[s3][c0 + 2] = bm2; s_pi[s3][c0 + 2] = bi2;
  s_pv[s3][c0 + 3] = bm3; s_pi[s3][c0 + 3] = bi3;
  __syncthreads();

  if (t < 256) {
    const int c = t & 31, g = t >> 5;
    float bv = s_pv[g * 8][c];
    int   bx = s_pi[g * 8][c];
    #pragma unroll
    for (int u = 1; u < 8; ++u) {
      const float v = s_pv[g * 8 + u][c];
      const int   x = s_pi[g * 8 + u][c];
      if (v > bv || (v == bv && x < bx)) { bv = v; bx = x; }
    }
    s2v[g][c] = bv; s2i[g][c] = bx;
  }
  __syncthreads();
  if (t < 32) {
    float bv = s2v[0][t];
    int   bx = s2i[0][t];
    #pragma unroll
    for (int g = 1; g < 8; ++g) {
      const float v = s2v[g][t];
      const int   x = s2i[g][t];
      if (v > bv || (v == bv && x < bx)) { bv = v; bx = x; }
    }
    const int im = bx / 28;
    s_peak[t] = (im << 8) | (bx - im * 28);
  }
  __syncthreads();

  // ---- Phase C: mask the register-resident values, nontemporal store ----
  const int pk0 = s_peak[c0 + 0], pk1 = s_peak[c0 + 1];
  const int pk2 = s_peak[c0 + 2], pk3 = s_peak[c0 + 3];
  const int im0 = pk0 >> 8, jm0 = pk0 & 255;
  const int im1 = pk1 >> 8, jm1 = pk1 & 255;
  const int im2 = pk2 >> 8, jm2 = pk2 & 255;
  const int im3 = pk3 >> 8, jm3 = pk3 & 255;

  int i = s3 / 28;
  int j = s3 - i * 28;
  constexpr float MS = -(TAU / 7.0f);   // compile-time fp32

#define APPLYK(k) { f32x4 o; \
    o.x = vv##k.x * fmaxf(fmaf((float)(iabs(i - im0) + iabs(j - jm0)), MS, TAU), -TAU); \
    o.y = vv##k.y * fmaxf(fmaf((float)(iabs(i - im1) + iabs(j - jm1)), MS, TAU), -TAU); \
    o.z = vv##k.z * fmaxf(fmaf((float)(iabs(i - im2) + iabs(j - jm2)), MS, TAU), -TAU); \
    o.w = vv##k.w * fmaxf(fmaf((float)(iabs(i - im3) + iabs(j - jm3)), MS, TAU), -TAU); \
    __builtin_nontemporal_store(o, dst + (size_t)(k) * KSTR); \
    j += 8; i += 2; if (j >= 28) { j -= 28; ++i; } }   // p += 64 -> (i,j) update
  LIST12(APPLYK)
#undef APPLYK
  if (tail) {
    f32x4 o;
    o.x = vv12.x * fmaxf(fmaf((float)(iabs(i - im0) + iabs(j - jm0)), MS, TAU), -TAU);
    o.y = vv12.y * fmaxf(fmaf((float)(iabs(i - im1) + iabs(j - jm1)), MS, TAU), -TAU);
    o.z = vv12.z * fmaxf(fmaf((float)(iabs(i - im2) + iabs(j - jm2)), MS, TAU), -TAU);
    o.w = vv12.w * fmaxf(fmaf((float)(iabs(i - im3) + iabs(j - jm3)), MS, TAU), -TAU);
    __builtin_nontemporal_store(o, dst + (size_t)12 * KSTR);
  }
#undef LIST12
}

extern "C" void kernel_launch(void* const* d_in, const int* in_sizes, int n_in,
                              void* d_out, int out_size, void* d_ws, size_t ws_size,
                              hipStream_t stream) {
  const f32x4* in4  = (const f32x4*)d_in[0];
  f32x4*       out4 = (f32x4*)d_out;
  // One block per (batch, 32-channel group): 64 x 32 = 2048 blocks, 512 thr.
  fused_mask_kernel<<<BN * 32, 512, 0, stream>>>(in4, out4);
}